// Round 7
// baseline (187.328 us; speedup 1.0000x reference)
//
#include <hip/hip_runtime.h>
#include <hip/hip_bf16.h>

typedef __bf16 bf16;
typedef __bf16 bf16x2 __attribute__((ext_vector_type(2)));
typedef __bf16 bf16x4 __attribute__((ext_vector_type(4)));
typedef __bf16 bf16x8 __attribute__((ext_vector_type(8)));
typedef float f32x4 __attribute__((ext_vector_type(4)));

// (1/16) * log2(e): softmax scale folded into exp2
#define SM_C 0.09016994374947424f

typedef __attribute__((address_space(1))) const void as1_void;
typedef __attribute__((address_space(3))) void as3_void;

// ---------------------------------------------------------------------------
// prep: Wq/Wk/Wv/Wo [k][n] f32 -> Wt[mat][n][k] bf16. LDS-tiled 32x32
// transpose. grid 256 = 4 mats x 64 tiles.
// ---------------------------------------------------------------------------
__global__ __launch_bounds__(256) void transpose_w(
    const float* __restrict__ Wq, const float* __restrict__ Wk,
    const float* __restrict__ Wv, const float* __restrict__ Wo,
    bf16* __restrict__ Wt)
{
    __shared__ float T[32][33];
    const int bid = blockIdx.x;
    const int m = bid >> 6, tile = bid & 63;
    const int tn0 = (tile >> 3) * 32, tk0 = (tile & 7) * 32;
    const float* W = (m == 0) ? Wq : (m == 1) ? Wk : (m == 2) ? Wv : Wo;

    const int t = threadIdx.x;
    const int r = t >> 3, c4 = (t & 7) * 4;

    f32x4 v = *(const f32x4*)(W + (size_t)(tk0 + r) * 256 + tn0 + c4);
#pragma unroll
    for (int j = 0; j < 4; ++j) T[r][c4 + j] = v[j];
    __syncthreads();

    bf16x4 ov;
#pragma unroll
    for (int j = 0; j < 4; ++j) ov[j] = (bf16)T[c4 + j][r];
    *(bf16x4*)(Wt + (size_t)m * 65536 + (size_t)(tn0 + r) * 256 + tk0 + c4) = ov;
}

// ---------------------------------------------------------------------------
// Fused QKV as ONE GEMM (unchanged from round 6, incl. LDS-transit Q/K
// epilogue). grid (256 bm, 6 bn), 256 thr, 128x128 tile, BK=64.
// ---------------------------------------------------------------------------
__global__ __launch_bounds__(256, 3) void qkv_gemm(
    const float* __restrict__ X, const bf16* __restrict__ Wt,
    const float* __restrict__ bq, const float* __restrict__ bk,
    const float* __restrict__ bv,
    bf16* __restrict__ Qo, bf16* __restrict__ Ko, bf16* __restrict__ Vto)
{
    __shared__ __align__(16) char qsmem[36864];
    bf16* const Xs  = (bf16*)qsmem;            // [128][72]
    bf16* const Ws_ = (bf16*)(qsmem + 18432);  // [128][72]
    bf16* const Cs  = (bf16*)qsmem;            // epilogue: [128][132]

    const int t    = threadIdx.x;
    const int lane = t & 63, wv = t >> 6;
    const int quad = lane >> 4, l16 = lane & 15;
    const int bm   = blockIdx.x;
    const int bn   = blockIdx.y;
    const int proj = bn >> 1;

    const bf16* W = Wt + (size_t)proj * 65536 + (size_t)(bn & 1) * 32768;
    const float* bias = (proj == 0) ? bq : (proj == 1) ? bk : bv;

    const int m0 = t >> 3;
    const int c0 = (t & 7) * 8;

    const f32x4 zero = {0.0f, 0.0f, 0.0f, 0.0f};
    f32x4 acc[2][8];
#pragma unroll
    for (int i = 0; i < 2; ++i)
#pragma unroll
        for (int j = 0; j < 8; ++j) acc[i][j] = zero;

    f32x4 xa[4], xb[4]; bf16x8 wp[4];
#pragma unroll
    for (int p = 0; p < 4; ++p) {
        const float* px = X + (size_t)(bm * 128 + m0 + p * 32) * 256 + c0;
        xa[p] = *(const f32x4*)px; xb[p] = *(const f32x4*)(px + 4);
        wp[p] = *(const bf16x8*)(W + (size_t)(m0 + p * 32) * 256 + c0);
    }

    for (int kt = 0; kt < 4; ++kt) {
#pragma unroll
        for (int p = 0; p < 4; ++p) {
            bf16x8 r;
#pragma unroll
            for (int j = 0; j < 4; ++j) { r[j] = (bf16)xa[p][j]; r[j + 4] = (bf16)xb[p][j]; }
            *(bf16x8*)(Xs + (m0 + p * 32) * 72 + c0) = r;
            *(bf16x8*)(Ws_ + (m0 + p * 32) * 72 + c0) = wp[p];
        }
        __syncthreads();

        if (kt < 3) {
#pragma unroll
            for (int p = 0; p < 4; ++p) {
                const float* px = X + (size_t)(bm * 128 + m0 + p * 32) * 256 + (kt + 1) * 64 + c0;
                xa[p] = *(const f32x4*)px; xb[p] = *(const f32x4*)(px + 4);
                wp[p] = *(const bf16x8*)(W + (size_t)(m0 + p * 32) * 256 + (kt + 1) * 64 + c0);
            }
        }

#pragma unroll
        for (int ks = 0; ks < 2; ++ks) {
            bf16x8 a[2], bb[8];
#pragma unroll
            for (int mt = 0; mt < 2; ++mt)
                a[mt] = *(const bf16x8*)(Xs + (wv * 32 + mt * 16 + l16) * 72 + ks * 32 + quad * 8);
#pragma unroll
            for (int nt = 0; nt < 8; ++nt)
                bb[nt] = *(const bf16x8*)(Ws_ + (nt * 16 + l16) * 72 + ks * 32 + quad * 8);
#pragma unroll
            for (int mt = 0; mt < 2; ++mt)
#pragma unroll
                for (int nt = 0; nt < 8; ++nt)
                    acc[mt][nt] = __builtin_amdgcn_mfma_f32_16x16x32_bf16(
                        a[mt], bb[nt], acc[mt][nt], 0, 0, 0);
        }
        __syncthreads();
    }

    // epilogue
    if (proj == 2) {
#pragma unroll
        for (int nt = 0; nt < 8; ++nt) {
            int col = (bn & 1) * 128 + nt * 16 + l16;
            float bvv = bias[col];
#pragma unroll
            for (int mt = 0; mt < 2; ++mt) {
                int grow0 = bm * 128 + wv * 32 + mt * 16 + quad * 4;
                bf16x4 pk;
#pragma unroll
                for (int r = 0; r < 4; ++r) pk[r] = (bf16)(acc[mt][nt][r] + bvv);
                int b = grow0 >> 10, m = grow0 & 1023;
                *(bf16x4*)(Vto + (size_t)b * 262144 + (size_t)col * 1024 + m) = pk;
            }
        }
    } else {
        bf16* dst = (proj == 0) ? Qo : Ko;
#pragma unroll
        for (int nt = 0; nt < 8; ++nt) {
            float bvv = bias[(bn & 1) * 128 + nt * 16 + l16];
#pragma unroll
            for (int mt = 0; mt < 2; ++mt)
#pragma unroll
                for (int r = 0; r < 4; ++r)
                    Cs[(wv * 32 + mt * 16 + quad * 4 + r) * 132 + nt * 16 + l16] =
                        (bf16)(acc[mt][nt][r] + bvv);
        }
        __syncthreads();
#pragma unroll
        for (int i = 0; i < 8; ++i) {
            int chunk = i * 256 + t;
            int row = chunk >> 4, cc = chunk & 15;
            bf16x8 v = *(const bf16x8*)(Cs + row * 132 + cc * 8);
            *(bf16x8*)(dst + (size_t)(bm * 128 + row) * 256 + (bn & 1) * 128 + cc * 8) = v;
        }
    }
}

// ---------------------------------------------------------------------------
// Flash attention + fused O-projection, v3.
// 256 thr / 4 waves, grid (32 b, 8 qt), 80 KB LDS -> 2 blocks/CU (barrier
// drains of one block hide under the other block's MFMA).
// Each wave owns 32 q-rows (mt=2): every K/V LDS fragment feeds 2 MFMAs ->
// per-dispatch frag reads halve vs the 16-row design (which was ~78%
// LDS-port-bound by cycle budget). No kv-split -> no merge, no staging regs:
// K and V both staged via global_load_lds (linear LDS dest, inverse-swizzled
// global source; read-side XOR matches — rule 21 pattern, verified in R5).
// Swapped QK^T (mfma(K,Q)): lane holds kv-consecutive P -> packed bf16x2
// P writes into per-wave 1 KB tile (R5-verified layout).
// LDS map (82,?0 B total = 81920):
//   loop: Ks[2] @0 (2x16384, [32]x512B swz) | Vs[2] @32768 (2x16384,
//         [256]x64B swz) | P @65536 + wv*1024
//   epi:  Os @0 ([128]x512B swz, 64 KB) | Wos @65536 ([32]x512B swz, 16 KB)
// ---------------------------------------------------------------------------
__global__ __launch_bounds__(256, 2) void flash_attn(
    const bf16* __restrict__ Qr, const bf16* __restrict__ K,
    const bf16* __restrict__ Vt, const bf16* __restrict__ Wo,
    const float* __restrict__ bo, float* __restrict__ out)
{
    __shared__ __align__(16) char smem[81920];

    const int t    = threadIdx.x;
    const int lane = t & 63, wv = t >> 6;          // wv 0..3
    const int quad = lane >> 4, l16 = lane & 15;
    const int b  = blockIdx.x;   // 0..31  (fastest -> XCD = b % 8)
    const int qt = blockIdx.y;   // 0..7

    // Q fragments (B operand of swapped QK^T): q = qt*128 + wv*32 + mt*16 + l16
    bf16x8 qf[2][8];
#pragma unroll
    for (int mt = 0; mt < 2; ++mt) {
        const bf16* qp = Qr + ((size_t)b * 1024 + qt * 128 + wv * 32 + mt * 16 + l16) * 256 + quad * 8;
#pragma unroll
        for (int ks = 0; ks < 8; ++ks)
            qf[mt][ks] = *(const bf16x8*)(qp + ks * 32);
    }

    const f32x4 zero = {0.0f, 0.0f, 0.0f, 0.0f};
    f32x4 o[2][16];
#pragma unroll
    for (int mt = 0; mt < 2; ++mt)
#pragma unroll
        for (int n = 0; n < 16; ++n) o[mt][n] = zero;
    float lst[2] = {0.f, 0.f};

    // K tile T -> LDS buf: 16 x 1KB chunks; dest linear, source pre-swizzled
    // (reader uses slot ^= row&7 at 16B granularity).
    auto gloadK = [&](int T, int buf) {
#pragma unroll
        for (int p = 0; p < 4; ++p) {
            int chunk = wv * 4 + p;
            int row   = chunk * 2 + (lane >> 5);      // 0..31 kv
            int s     = (lane & 31) ^ (row & 7);      // source 16B slot
            const bf16* gsrc = K + ((size_t)b * 1024 + T * 32 + row) * 256 + s * 8;
            __builtin_amdgcn_global_load_lds((as1_void*)gsrc,
                (as3_void*)(smem + buf * 16384 + chunk * 1024), 16, 0, 0);
        }
    };
    // V tile T -> LDS buf: [256 ch][64B], 16 x 1KB chunks; slot ^= row&3.
    auto gloadV = [&](int T, int buf) {
#pragma unroll
        for (int p = 0; p < 4; ++p) {
            int chunk = wv * 4 + p;
            int row   = chunk * 16 + (lane >> 2);     // 0..255 channel
            int s     = (lane & 3) ^ (row & 3);       // source 16B slot (kv/8)
            const bf16* gsrc = Vt + (size_t)b * 262144 + (size_t)row * 1024 + T * 32 + s * 8;
            __builtin_amdgcn_global_load_lds((as1_void*)gsrc,
                (as3_void*)(smem + 32768 + buf * 16384 + chunk * 1024), 16, 0, 0);
        }
    };

    char* const Pb = smem + 65536 + wv * 1024;     // per-wave [16 q][64B] swz
    const int psw = (l16 & 7) << 4;

    gloadK(0, 0); gloadV(0, 0);

    for (int j = 0; j < 32; ++j) {
        const int buf = j & 1;
        __syncthreads();   // tile j gloads drained & visible; buf^1 reads done

        if (j < 31) { gloadK(j + 1, buf ^ 1); gloadV(j + 1, buf ^ 1); }

        // ---- swapped S = K Q^T: C col = q (l16), row = kv (n*16+quad*4+r)
        f32x4 s2[2][2];
        s2[0][0] = zero; s2[0][1] = zero; s2[1][0] = zero; s2[1][1] = zero;
        const char* Kb = smem + buf * 16384;
#pragma unroll
        for (int ks = 0; ks < 8; ++ks) {
#pragma unroll
            for (int n = 0; n < 2; ++n) {
                bf16x8 kb = *(const bf16x8*)(Kb + (n * 16 + l16) * 512 +
                                             (((ks * 4 + quad) ^ (l16 & 7)) << 4));
                s2[0][n] = __builtin_amdgcn_mfma_f32_16x16x32_bf16(kb, qf[0][ks], s2[0][n], 0, 0, 0);
                s2[1][n] = __builtin_amdgcn_mfma_f32_16x16x32_bf16(kb, qf[1][ks], s2[1][n], 0, 0, 0);
            }
        }

        // ---- softmax + packed P (kv-consecutive pairs) + A-frag read
        bf16x8 af[2];
#pragma unroll
        for (int mt = 0; mt < 2; ++mt) {
#pragma unroll
            for (int n = 0; n < 2; ++n) {
#pragma unroll
                for (int h = 0; h < 2; ++h) {
                    float p0 = __builtin_amdgcn_exp2f(s2[mt][n][2 * h] * SM_C);
                    float p1 = __builtin_amdgcn_exp2f(s2[mt][n][2 * h + 1] * SM_C);
                    lst[mt] += p0 + p1;
                    bf16x2 pk; pk[0] = (bf16)p0; pk[1] = (bf16)p1;
                    *(bf16x2*)(Pb + ((l16 * 64 + n * 32 + quad * 8 + h * 4) ^ psw)) = pk;
                }
            }
            af[mt] = *(const bf16x8*)(Pb + ((l16 * 64 + quad * 16) ^ psw));
        }

        // ---- O += P V  (V-frag read once, feeds both mt)
        const char* Vb = smem + 32768 + buf * 16384;
#pragma unroll
        for (int n = 0; n < 16; ++n) {
            bf16x8 vb = *(const bf16x8*)(Vb + (n * 16 + l16) * 64 +
                                         ((quad ^ (l16 & 3)) << 4));
            o[0][n] = __builtin_amdgcn_mfma_f32_16x16x32_bf16(af[0], vb, o[0][n], 0, 0, 0);
            o[1][n] = __builtin_amdgcn_mfma_f32_16x16x32_bf16(af[1], vb, o[1][n], 0, 0, 0);
        }
    }

    __syncthreads();   // loop LDS dead

    // ---- softmax denominators (lane holds full sum for q-col l16 after xors)
#pragma unroll
    for (int mt = 0; mt < 2; ++mt) {
        lst[mt] += __shfl_xor(lst[mt], 16, 64);
        lst[mt] += __shfl_xor(lst[mt], 32, 64);
    }
    float inv[2][4];
#pragma unroll
    for (int mt = 0; mt < 2; ++mt)
#pragma unroll
        for (int r = 0; r < 4; ++r)
            inv[mt][r] = 1.0f / __shfl(lst[mt], quad * 4 + r, 64);

    // ---- normalized attended -> Os ([128]x512B, XOR-swizzled rows)
#pragma unroll
    for (int mt = 0; mt < 2; ++mt)
#pragma unroll
        for (int n = 0; n < 16; ++n)
#pragma unroll
            for (int r = 0; r < 4; ++r) {
                int row = wv * 32 + mt * 16 + quad * 4 + r;
                int col = n * 16 + l16;
                *(bf16*)(smem + row * 512 + ((col * 2) ^ ((row & 7) << 4))) =
                    (bf16)(o[mt][n][r] * inv[mt][r]);
            }

    // ---- fused O-projection: 8 slices of 32 out-cols; Wos @65536 (16 KB swz)
    const size_t orow0 = (size_t)b * 1024 + qt * 128 + wv * 32;
    for (int sl = 0; sl < 8; ++sl) {
        __syncthreads();     // sl0: Os visible; sl>0: prev Wos reads done
#pragma unroll
        for (int p = 0; p < 4; ++p) {
            int chunk = wv * 4 + p;
            int row   = chunk * 2 + (lane >> 5);      // 0..31 (out-col local)
            int s     = (lane & 31) ^ (row & 7);
            const bf16* gsrc = Wo + (size_t)(sl * 32 + row) * 256 + s * 8;
            __builtin_amdgcn_global_load_lds((as1_void*)gsrc,
                (as3_void*)(smem + 65536 + chunk * 1024), 16, 0, 0);
        }
        __syncthreads();     // Wos ready (vmcnt drained before barrier)

        f32x4 acc[2][2];
        acc[0][0] = zero; acc[0][1] = zero; acc[1][0] = zero; acc[1][1] = zero;
#pragma unroll
        for (int ks = 0; ks < 8; ++ks) {
            bf16x8 a[2], bb[2];
#pragma unroll
            for (int rt = 0; rt < 2; ++rt) {
                int row = wv * 32 + rt * 16 + l16;
                a[rt] = *(const bf16x8*)(smem + row * 512 +
                                         (((ks * 4 + quad) ^ (l16 & 7)) << 4));
            }
#pragma unroll
            for (int ct = 0; ct < 2; ++ct) {
                int row = ct * 16 + l16;
                bb[ct] = *(const bf16x8*)(smem + 65536 + row * 512 +
                                          (((ks * 4 + quad) ^ (l16 & 7)) << 4));
            }
#pragma unroll
            for (int rt = 0; rt < 2; ++rt)
#pragma unroll
                for (int ct = 0; ct < 2; ++ct)
                    acc[rt][ct] = __builtin_amdgcn_mfma_f32_16x16x32_bf16(
                        a[rt], bb[ct], acc[rt][ct], 0, 0, 0);
        }

#pragma unroll
        for (int ct = 0; ct < 2; ++ct) {
            int col = sl * 32 + ct * 16 + l16;
            float bvv = bo[col];
#pragma unroll
            for (int rt = 0; rt < 2; ++rt)
#pragma unroll
                for (int r = 0; r < 4; ++r) {
                    size_t row = orow0 + rt * 16 + quad * 4 + r;
                    out[row * 256 + col] = acc[rt][ct][r] + bvv;
                }
        }
    }
}

// ---------------------------------------------------------------------------
extern "C" void kernel_launch(void* const* d_in, const int* in_sizes, int n_in,
                              void* d_out, int out_size, void* d_ws, size_t ws_size,
                              hipStream_t stream)
{
    (void)in_sizes; (void)n_in; (void)out_size; (void)ws_size;
    const float* X  = (const float*)d_in[0];
    const float* Wq = (const float*)d_in[1];
    const float* bq = (const float*)d_in[2];
    const float* Wk = (const float*)d_in[3];
    const float* bk = (const float*)d_in[4];
    const float* Wv = (const float*)d_in[5];
    const float* bv = (const float*)d_in[6];
    const float* Wo = (const float*)d_in[7];
    const float* bo = (const float*)d_in[8];
    float* out = (float*)d_out;

    const size_t NTOK = (size_t)32768 * 256;

    // workspace: Wt (4 mats = 512 KB) + Q + K + Vt
    bf16* Wt  = (bf16*)d_ws;
    bf16* Qw  = (bf16*)d_ws + 262144;
    bf16* Kw  = Qw + NTOK;
    bf16* Vtw = Kw + NTOK;

    transpose_w<<<256, 256, 0, stream>>>(Wq, Wk, Wv, Wo, Wt);
    qkv_gemm   <<<dim3(256, 6), 256, 0, stream>>>(X, Wt, bq, bk, bv, Qw, Kw, Vtw);
    flash_attn <<<dim3(32, 8),  256, 0, stream>>>(Qw, Kw, Vtw, Wt + 3 * 65536, bo, out);
}